// Round 4
// baseline (453.582 us; speedup 1.0000x reference)
//
#include <hip/hip_runtime.h>
#include <math.h>

#define NOP 4096
#define NTASK 64
#define NTENSOR 32768
#define NLINK 1024
#define NPLACE (NOP*NTASK)
#define CAP 64
#define NBLK 260           // mega grid: 4 task blocks + 256 op blocks (16 ops each)

// ---- workspace layout (units of 4 bytes); ws is plenty (>=24MB needed) ----
enum : int {
  O_CNT_PREV  = 0,                          // 4096 ints
  O_CNT_SUCC  = O_CNT_PREV + NOP,
  O_CNT_LINK  = O_CNT_SUCC + NOP,           // 64
  O_BAR       = O_CNT_LINK + 64,            // 128 (cnt at +0, gen at +64)
  O_SEF_PREV  = O_BAR + 128,                // NOP*8
  O_SEF_SUCC  = O_SEF_PREV + NOP*8,
  O_SEF_LINK  = O_SEF_SUCC + NOP*8,         // 64*8
  O_SEF_PLACE = O_SEF_LINK + 64*8,          // 64*8
  O_SEF_SERVE = O_SEF_PLACE + 64*8,         // NOP*8
  O_OP_A      = O_SEF_SERVE + NOP*8,        // NOP*64
  O_OP_B      = O_OP_A + NOP*64,
  O_TASK_A    = O_OP_B + NOP*64,            // 64*64
  O_TASK_B    = O_TASK_A + 64*64,
  O_BPLACE    = O_TASK_B + 64*64,           // NPLACE
  O_MOPP      = O_BPLACE + NPLACE,          // 2 * 256*64 op-sum partials
  O_MTPP      = O_MOPP + 2*256*64,          // 2 * 4*64
  O_SPLP      = O_MTPP + 2*4*64,            // 256*512 place-ef partials
  O_CSRP_PREV = O_SPLP + 256*512,           // NOP*CAP ints
  O_CSRP_SUCC = O_CSRP_PREV + NOP*CAP,
  O_CSRP_LINK = O_CSRP_SUCC + NOP*CAP,      // 64*CAP
  O_EFS_PREV  = O_CSRP_LINK + 64*CAP,       // NOP*CAP*8 floats
  O_EFS_SUCC  = O_EFS_PREV + NOP*CAP*8,
  O_EFS_LINK  = O_EFS_SUCC + NOP*CAP*8,     // 64*CAP*8
  O_TOTAL     = O_EFS_LINK + 64*CAP*8
};

__device__ __forceinline__ float elu1(float x) { return x > 0.f ? x : expm1f(x); }

__device__ __forceinline__ void fma4(float4& a, const float s, const float4 w) {
  a.x = fmaf(s, w.x, a.x);
  a.y = fmaf(s, w.y, a.y);
  a.z = fmaf(s, w.z, a.z);
  a.w = fmaf(s, w.w, a.w);
}

// device-scope generation barrier; all NBLK blocks guaranteed co-resident
__device__ __forceinline__ void gridbar(int* bar) {
  __syncthreads();
  if (threadIdx.x == 0) {
    __threadfence();
    int* cnt = bar;
    int* gen = bar + 64;
    const int g = __hip_atomic_load(gen, __ATOMIC_RELAXED, __HIP_MEMORY_SCOPE_AGENT);
    const int my = __hip_atomic_fetch_add(cnt, 1, __ATOMIC_ACQ_REL, __HIP_MEMORY_SCOPE_AGENT);
    if (my == NBLK - 1) {
      __hip_atomic_store(cnt, 0, __ATOMIC_RELAXED, __HIP_MEMORY_SCOPE_AGENT);
      __hip_atomic_fetch_add(gen, 1, __ATOMIC_ACQ_REL, __HIP_MEMORY_SCOPE_AGENT);
    } else {
      while (__hip_atomic_load(gen, __ATOMIC_ACQUIRE, __HIP_MEMORY_SCOPE_AGENT) == g)
        __builtin_amdgcn_s_sleep(4);
    }
    __threadfence();
  }
  __syncthreads();
}

// ---------------- embeddings (blocks 0..255: ops; block 256: tasks + zeroing) ----------------
__global__ __launch_bounds__(256) void k_embed(
    const float* __restrict__ opA, const float* __restrict__ opW, const float* __restrict__ opb,
    const float* __restrict__ taskA, const float* __restrict__ taskW, const float* __restrict__ taskb,
    float* __restrict__ ws)
{
  const int tid = threadIdx.x;
  const int bid = blockIdx.x;
  if (bid < 256) {
    __shared__ float sW[8192];
    __shared__ float sA[16*260];
    __shared__ float4 red[256];
    const int obase = bid * 16;
    for (int i = tid; i < 4096; i += 256) {
      const int o = i >> 8, k = i & 255;
      sA[o*260 + k] = opA[(size_t)(obase + o)*256 + k];
    }
    const int o = tid >> 4, hq = tid & 15, h0 = hq*4;
    float4 acc = *(const float4*)&opb[h0];
    for (int half = 0; half < 2; ++half) {
      __syncthreads();
      for (int i = tid*4; i < 8192; i += 1024)
        *(float4*)&sW[i] = *(const float4*)&opW[half*8192 + i];
      __syncthreads();
      const float* a = &sA[o*260 + half*128];
      for (int k = 0; k < 128; ++k)
        fma4(acc, a[k], *(const float4*)&sW[k*64 + h0]);
    }
    acc.x = elu1(acc.x); acc.y = elu1(acc.y); acc.z = elu1(acc.z); acc.w = elu1(acc.w);
    *(float4*)&ws[O_OP_A + (size_t)(obase + o)*64 + h0] = acc;
    red[tid] = acc;
    __syncthreads();
    if (tid < 16) {
      float4 s = make_float4(0.f,0.f,0.f,0.f);
      for (int g = 0; g < 16; ++g) {
        float4 v = red[g*16 + tid];
        s.x += v.x; s.y += v.y; s.z += v.z; s.w += v.w;
      }
      *(float4*)&ws[O_MOPP + bid*64 + tid*4] = s;   // parity 0 slot
    }
  } else {
    __shared__ float sA[64*65];
    __shared__ float sW[64*64];
    __shared__ float4 red[256];
    int* ib = (int*)ws;
    for (int i = tid; i < NOP*2 + 64 + 128; i += 256) ib[O_CNT_PREV + i] = 0;
    for (int i = tid; i < 4096; i += 256) {
      const int t = i >> 6, k = i & 63;
      sA[t*65 + k] = taskA[i];
    }
    for (int i = tid*4; i < 4096; i += 1024)
      *(float4*)&sW[i] = *(const float4*)&taskW[i];
    __syncthreads();
    const int og = tid >> 4, hq = tid & 15, h0 = hq*4;
    float4 msum = make_float4(0.f,0.f,0.f,0.f);
    for (int tg = 0; tg < 4; ++tg) {
      const int t = tg*16 + og;
      float4 acc = *(const float4*)&taskb[h0];
      const float* a = &sA[t*65];
      for (int k = 0; k < 64; ++k)
        fma4(acc, a[k], *(const float4*)&sW[k*64 + h0]);
      acc.x = elu1(acc.x); acc.y = elu1(acc.y); acc.z = elu1(acc.z); acc.w = elu1(acc.w);
      *(float4*)&ws[O_TASK_A + t*64 + h0] = acc;
      msum.x += acc.x; msum.y += acc.y; msum.z += acc.z; msum.w += acc.w;
    }
    red[tid] = msum;
    __syncthreads();
    if (tid < 16) {
      float4 s = make_float4(0.f,0.f,0.f,0.f);
      for (int g = 0; g < 16; ++g) {
        float4 v = red[g*16 + tid];
        s.x += v.x; s.y += v.y; s.z += v.z; s.w += v.w;
      }
      *(float4*)&ws[O_MTPP + tid*4] = s;   // parity 0, slot 0
    }
  }
}

// -------- edges (blocks 0..127) + place/serve (blocks 128..383) --------
__global__ __launch_bounds__(256) void k_edge_place(
    const float* __restrict__ tensor_feats, const float* __restrict__ link_feats,
    const float* __restrict__ place_feats,
    const int* __restrict__ prev_src, const int* __restrict__ prev_dst,
    const int* __restrict__ link_src, const int* __restrict__ link_dst,
    const float* __restrict__ eW, const float* __restrict__ eb,
    const float* __restrict__ finalW, float* __restrict__ ws)
{
  const int tid = threadIdx.x;
  const int bid = blockIdx.x;
  int* ib = (int*)ws;
  if (bid < 128) {
    __shared__ float sEW[384];
    __shared__ float sEB[24];
    for (int i = tid; i < 384; i += 256) sEW[i] = eW[i];
    if (tid < 24) sEB[tid] = eb[tid];
    __syncthreads();
    const int e = bid*256 + tid;
    float raw[16];
    *(float4*)&raw[0]  = *(const float4*)&tensor_feats[(size_t)e*16 + 0];
    *(float4*)&raw[4]  = *(const float4*)&tensor_feats[(size_t)e*16 + 4];
    *(float4*)&raw[8]  = *(const float4*)&tensor_feats[(size_t)e*16 + 8];
    *(float4*)&raw[12] = *(const float4*)&tensor_feats[(size_t)e*16 + 12];
    float efp[8], efs[8];
#pragma unroll
    for (int c = 0; c < 8; ++c) { efp[c] = sEB[8+c]; efs[c] = sEB[16+c]; }
#pragma unroll
    for (int k = 0; k < 16; ++k) {
      const float a = raw[k];
#pragma unroll
      for (int c = 0; c < 8; ++c) {
        efp[c] = fmaf(a, sEW[128 + k*8 + c], efp[c]);
        efs[c] = fmaf(a, sEW[256 + k*8 + c], efs[c]);
      }
    }
#pragma unroll
    for (int c = 0; c < 8; ++c) { efp[c] = elu1(efp[c]); efs[c] = elu1(efs[c]); }
    const int pd = prev_dst[e], ps = prev_src[e];
    {
      int pos = atomicAdd(&ib[O_CNT_PREV + pd], 1);
      if (pos < CAP) {
        ib[O_CSRP_PREV + pd*CAP + pos] = ps;
        float* dst = ws + O_EFS_PREV + ((size_t)pd*CAP + pos)*8;
        *(float4*)&dst[0] = make_float4(efp[0],efp[1],efp[2],efp[3]);
        *(float4*)&dst[4] = make_float4(efp[4],efp[5],efp[6],efp[7]);
      }
    }
    {
      int pos = atomicAdd(&ib[O_CNT_SUCC + ps], 1);
      if (pos < CAP) {
        ib[O_CSRP_SUCC + ps*CAP + pos] = pd;
        float* dst = ws + O_EFS_SUCC + ((size_t)ps*CAP + pos)*8;
        *(float4*)&dst[0] = make_float4(efs[0],efs[1],efs[2],efs[3]);
        *(float4*)&dst[4] = make_float4(efs[4],efs[5],efs[6],efs[7]);
      }
    }
    if (e < NLINK) {
      float rl[16];
      *(float4*)&rl[0]  = *(const float4*)&link_feats[(size_t)e*16 + 0];
      *(float4*)&rl[4]  = *(const float4*)&link_feats[(size_t)e*16 + 4];
      *(float4*)&rl[8]  = *(const float4*)&link_feats[(size_t)e*16 + 8];
      *(float4*)&rl[12] = *(const float4*)&link_feats[(size_t)e*16 + 12];
      float efl[8];
#pragma unroll
      for (int c = 0; c < 8; ++c) efl[c] = sEB[c];
#pragma unroll
      for (int k = 0; k < 16; ++k) {
        const float a = rl[k];
#pragma unroll
        for (int c = 0; c < 8; ++c) efl[c] = fmaf(a, sEW[k*8 + c], efl[c]);
      }
      const int ld = link_dst[e];
      int pos = atomicAdd(&ib[O_CNT_LINK + ld], 1);
      if (pos < CAP) {
        ib[O_CSRP_LINK + ld*CAP + pos] = link_src[e];
        float* dst = ws + O_EFS_LINK + ((size_t)ld*CAP + pos)*8;
        *(float4*)&dst[0] = make_float4(elu1(efl[0]),elu1(efl[1]),elu1(efl[2]),elu1(efl[3]));
        *(float4*)&dst[4] = make_float4(elu1(efl[4]),elu1(efl[5]),elu1(efl[6]),elu1(efl[7]));
      }
    }
  } else {
    __shared__ float sW3[128], sW4[128], sB3[8], sB4[8], sW1[8];
    __shared__ float pl[512];
    const int pbid = bid - 128;
    if (tid < 128) { sW3[tid] = eW[3*128 + tid]; sW4[tid] = eW[4*128 + tid]; }
    if (tid < 8) { sB3[tid] = eb[24+tid]; sB4[tid] = eb[32+tid]; sW1[tid] = finalW[64+tid]; }
    for (int i = tid; i < 512; i += 256) pl[i] = 0.f;
    __syncthreads();
    const int lane = tid & 63;
    const int wave = (pbid*256 + tid) >> 6;   // 0..1023, 4 op-rows each
    float pacc[8];
#pragma unroll
    for (int c = 0; c < 8; ++c) pacc[c] = 0.f;
    float* bplace = ws + O_BPLACE;
    float* sserve = ws + O_SEF_SERVE;
    for (int j = 0; j < 4; ++j) {
      const int i = wave*4 + j;
      const int e = i*64 + lane;
      float raw[16];
      *(float4*)&raw[0]  = *(const float4*)&place_feats[(size_t)e*16 + 0];
      *(float4*)&raw[4]  = *(const float4*)&place_feats[(size_t)e*16 + 4];
      *(float4*)&raw[8]  = *(const float4*)&place_feats[(size_t)e*16 + 8];
      *(float4*)&raw[12] = *(const float4*)&place_feats[(size_t)e*16 + 12];
      float efp[8], efs[8];
#pragma unroll
      for (int c = 0; c < 8; ++c) { efp[c] = sB3[c]; efs[c] = sB4[c]; }
#pragma unroll
      for (int k = 0; k < 16; ++k) {
        const float a = raw[k];
#pragma unroll
        for (int c = 0; c < 8; ++c) {
          efp[c] = fmaf(a, sW3[k*8 + c], efp[c]);
          efs[c] = fmaf(a, sW4[k*8 + c], efs[c]);
        }
      }
      float bp = 0.f;
#pragma unroll
      for (int c = 0; c < 8; ++c) {
        efp[c] = elu1(efp[c]);
        efs[c] = elu1(efs[c]);
        bp = fmaf(efp[c], sW1[c], bp);
        pacc[c] += efp[c];
      }
      bplace[e] = bp;
#pragma unroll
      for (int c = 0; c < 8; ++c) {
        float v = efs[c];
        for (int m = 32; m >= 1; m >>= 1) v += __shfl_xor(v, m, 64);
        if (lane == 0) sserve[i*8 + c] = v;
      }
    }
#pragma unroll
    for (int c = 0; c < 8; ++c) atomicAdd(&pl[lane*8 + c], pacc[c]);
    __syncthreads();
    for (int i = tid; i < 512; i += 256) ws[O_SPLP + pbid*512 + i] = pl[i];
  }
}

// ---------------- mega: sef sums -> 6 GNN layers -> final head ----------------
__global__ __launch_bounds__(256, 2) void k_mega(
    const float* __restrict__ gW, const float* __restrict__ gb,
    const float* __restrict__ finalW, const float* __restrict__ finalb,
    float* __restrict__ ws, float* __restrict__ out)
{
  __shared__ float smem[14816];
  const int tid = threadIdx.x;
  const int bid = blockIdx.x;
  int* ib = (int*)ws;
  int* bar = ib + O_BAR;

  // ---- phase S: SEF sums from padded slots + place-partial reduce ----
  if (bid < 256) {
    const bool isP = (bid < 128);
    const int bb = isP ? bid : bid - 128;
    const int d = bb*32 + (tid >> 3), c = tid & 7;
    const int cnt = min(ib[(isP ? O_CNT_PREV : O_CNT_SUCC) + d], CAP);
    const float* efs = ws + (isP ? O_EFS_PREV : O_EFS_SUCC) + (size_t)d*CAP*8;
    float s0=0.f,s1=0.f,s2=0.f,s3=0.f;
    int j = 0;
    for (; j+3 < cnt; j += 4) {
      s0 += efs[j*8+c]; s1 += efs[(j+1)*8+c]; s2 += efs[(j+2)*8+c]; s3 += efs[(j+3)*8+c];
    }
    for (; j < cnt; ++j) s0 += efs[j*8+c];
    ws[(isP ? O_SEF_PREV : O_SEF_SUCC) + d*8 + c] = (s0+s1)+(s2+s3);
  } else if (bid == 256) {
    for (int rep = 0; rep < 2; ++rep) {
      const int idx = rep*256 + tid;
      const int d = idx >> 3, c = idx & 7;
      const int cnt = min(ib[O_CNT_LINK + d], CAP);
      const float* efs = ws + O_EFS_LINK + (size_t)d*CAP*8;
      float s0=0.f,s1=0.f;
      int j = 0;
      for (; j+1 < cnt; j += 2) { s0 += efs[j*8+c]; s1 += efs[j*8+8+c]; }
      if (j < cnt) s0 += efs[j*8+c];
      ws[O_SEF_LINK + d*8 + c] = s0+s1;
    }
  } else if (bid == 257) {
    float s0=0.f,s1=0.f,s2=0.f,s3=0.f,s4=0.f,s5=0.f,s6=0.f,s7=0.f;
    for (int r = 0; r < 256; r += 4) {
      float2 v0 = *(const float2*)&ws[O_SPLP + (r+0)*512 + tid*2];
      float2 v1 = *(const float2*)&ws[O_SPLP + (r+1)*512 + tid*2];
      float2 v2 = *(const float2*)&ws[O_SPLP + (r+2)*512 + tid*2];
      float2 v3 = *(const float2*)&ws[O_SPLP + (r+3)*512 + tid*2];
      s0+=v0.x; s1+=v0.y; s2+=v1.x; s3+=v1.y; s4+=v2.x; s5+=v2.y; s6+=v3.x; s7+=v3.y;
    }
    ws[O_SEF_PLACE + tid*2]     = (s0+s2)+(s4+s6);
    ws[O_SEF_PLACE + tid*2 + 1] = (s1+s3)+(s5+s7);
  }
  gridbar(bar);

  float4 xkeep = make_float4(0.f,0.f,0.f,0.f);

  for (int l = 0; l < 6; ++l) {
    const int rpar = l & 1, wpar = 1 - rpar;
    const float* op_in   = ws + (rpar ? O_OP_B : O_OP_A);
    float*       op_out  = ws + (rpar ? O_OP_A : O_OP_B);
    const float* task_in = ws + (rpar ? O_TASK_B : O_TASK_A);
    float*       task_out= ws + (rpar ? O_TASK_A : O_TASK_B);

    if (bid >= 4) {
      // ---------------- op update: 16 ops ----------------
      float* sWp    = smem;            // 4608
      float* sWs    = smem + 4608;     // 4608
      float* sWeS   = smem + 9216;     // 512
      float* vp     = smem + 9728;     // 256
      float* sums_p = smem + 9984;     // 16*68
      float* sums_s = smem + 11072;    // 16*68
      float* sGB    = smem + 12160;    // 128
      float* sef    = smem + 12288;    // 384
      float* mop    = smem + 12672;    // 64
      int* idxp_s   = (int*)(smem + 12736);  // 1024
      int* idxs_s   = (int*)(smem + 13760);  // 1024
      int* cp_s     = (int*)(smem + 14784);  // 16
      int* cs_s     = (int*)(smem + 14800);  // 16

      const int obase = (bid - 4)*16;
      const float* gWprev  = gW + (size_t)((6  + l)*72)*64;
      const float* gWsucc  = gW + (size_t)((12 + l)*72)*64;
      const float* gWserve = gW + (size_t)((24 + l)*72)*64;

      for (int i = tid*4; i < 4608; i += 1024) {
        *(float4*)&sWp[i] = *(const float4*)&gWprev[i];
        *(float4*)&sWs[i] = *(const float4*)&gWsucc[i];
      }
      if (tid*4 < 512) *(float4*)&sWeS[tid*4] = *(const float4*)&gWserve[4096 + tid*4];
      if (tid < 16) {
        cp_s[tid] = ib[O_CNT_PREV + obase + tid];
        cs_s[tid] = ib[O_CNT_SUCC + obase + tid];
      }
      for (int i = tid; i < 16*CAP; i += 256) {
        const int o = i >> 6, j = i & 63;
        if (j < ib[O_CNT_PREV + obase + o]) idxp_s[i] = ib[O_CSRP_PREV + (obase+o)*CAP + j];
        if (j < ib[O_CNT_SUCC + obase + o]) idxs_s[i] = ib[O_CSRP_SUCC + (obase+o)*CAP + j];
      }
      if (tid < 128) {
        sGB[tid] = (tid < 64) ? gb[(6+l)*64 + tid] : gb[(12+l)*64 + (tid-64)];
        sef[tid]       = ws[O_SEF_PREV + obase*8 + tid];
        sef[128 + tid] = ws[O_SEF_SUCC + obase*8 + tid];
      } else {
        sef[256 + (tid & 127)] = ws[O_SEF_SERVE + obase*8 + (tid & 127)];
      }
      {
        const int col = tid & 63, g = tid >> 6;
        const float* mtpp = ws + O_MTPP + rpar*256;
        const int nst = (l == 0) ? 1 : 4;
        float acc = (g == 0) ? gb[(24+l)*64 + col] : 0.f;
        for (int kk = 0; kk < 16; ++kk) {
          const int k = g*16 + kk;
          float mt = 0.f;
          for (int s = 0; s < nst; ++s) mt += mtpp[s*64 + k];
          acc = fmaf(mt*(1.f/64.f), gWserve[k*64 + col], acc);
        }
        vp[g*64 + col] = acc;
      }
      if (tid < 64) mop[tid] = 0.f;
      __syncthreads();

      // per-wave gather (each wave feeds only its own 4 ops)
      const int wv = tid >> 6, lane = tid & 63;
      for (int oo = 0; oo < 4; ++oo) {
        const int o = wv*4 + oo;
        {
          const int pe = min(cp_s[o], CAP);
          float s0=0.f,s1=0.f,s2=0.f,s3=0.f;
          int p = 0;
          for (; p+3 < pe; p += 4) {
            s0 += op_in[(size_t)idxp_s[o*CAP+p  ]*64 + lane];
            s1 += op_in[(size_t)idxp_s[o*CAP+p+1]*64 + lane];
            s2 += op_in[(size_t)idxp_s[o*CAP+p+2]*64 + lane];
            s3 += op_in[(size_t)idxp_s[o*CAP+p+3]*64 + lane];
          }
          for (; p < pe; ++p) s0 += op_in[(size_t)idxp_s[o*CAP+p]*64 + lane];
          sums_p[o*68 + lane] = (s0+s1)+(s2+s3);
        }
        {
          const int pe = min(cs_s[o], CAP);
          float s0=0.f,s1=0.f,s2=0.f,s3=0.f;
          int p = 0;
          for (; p+3 < pe; p += 4) {
            s0 += op_in[(size_t)idxs_s[o*CAP+p  ]*64 + lane];
            s1 += op_in[(size_t)idxs_s[o*CAP+p+1]*64 + lane];
            s2 += op_in[(size_t)idxs_s[o*CAP+p+2]*64 + lane];
            s3 += op_in[(size_t)idxs_s[o*CAP+p+3]*64 + lane];
          }
          for (; p < pe; ++p) s0 += op_in[(size_t)idxs_s[o*CAP+p]*64 + lane];
          sums_s[o*68 + lane] = (s0+s1)+(s2+s3);
        }
      }

      // matmul: thread -> (op tid>>4, cols (tid&15)*4 ..+3)
      const int oL = tid >> 4, h0 = (tid & 15)*4;
      const int d = obase + oL;
      float4 up = make_float4(0.f,0.f,0.f,0.f);
      float4 us = make_float4(0.f,0.f,0.f,0.f);
      const int cp = cp_s[oL];
      if (cp > 0) {
        float4 a = make_float4(0.f,0.f,0.f,0.f);
        for (int k = 0; k < 64; ++k)
          fma4(a, sums_p[oL*68 + k], *(const float4*)&sWp[k*64 + h0]);
#pragma unroll
        for (int cc = 0; cc < 8; ++cc)
          fma4(a, sef[oL*8 + cc], *(const float4*)&sWp[4096 + cc*64 + h0]);
        const float r = 1.f/(float)cp;
        up.x = fmaf(a.x, r, sGB[h0+0]);
        up.y = fmaf(a.y, r, sGB[h0+1]);
        up.z = fmaf(a.z, r, sGB[h0+2]);
        up.w = fmaf(a.w, r, sGB[h0+3]);
      }
      const int cs = cs_s[oL];
      if (cs > 0) {
        float4 a = make_float4(0.f,0.f,0.f,0.f);
        for (int k = 0; k < 64; ++k)
          fma4(a, sums_s[oL*68 + k], *(const float4*)&sWs[k*64 + h0]);
#pragma unroll
        for (int cc = 0; cc < 8; ++cc)
          fma4(a, sef[128 + oL*8 + cc], *(const float4*)&sWs[4096 + cc*64 + h0]);
        const float r = 1.f/(float)cs;
        us.x = fmaf(a.x, r, sGB[64 + h0+0]);
        us.y = fmaf(a.y, r, sGB[64 + h0+1]);
        us.z = fmaf(a.z, r, sGB[64 + h0+2]);
        us.w = fmaf(a.w, r, sGB[64 + h0+3]);
      }
      float4 ug;
      {
        const float4 v0 = *(const float4*)&vp[h0];
        const float4 v1 = *(const float4*)&vp[64 + h0];
        const float4 v2 = *(const float4*)&vp[128 + h0];
        const float4 v3 = *(const float4*)&vp[192 + h0];
        ug.x = (v0.x+v1.x)+(v2.x+v3.x);
        ug.y = (v0.y+v1.y)+(v2.y+v3.y);
        ug.z = (v0.z+v1.z)+(v2.z+v3.z);
        ug.w = (v0.w+v1.w)+(v2.w+v3.w);
#pragma unroll
        for (int cc = 0; cc < 8; ++cc)
          fma4(ug, sef[256 + oL*8 + cc]*(1.f/64.f), *(const float4*)&sWeS[cc*64 + h0]);
      }
      float4 x = *(const float4*)&op_in[(size_t)d*64 + h0];
      x.x = elu1(x.x + (up.x + us.x + ug.x)*(1.f/3.f));
      x.y = elu1(x.y + (up.y + us.y + ug.y)*(1.f/3.f));
      x.z = elu1(x.z + (up.z + us.z + ug.z)*(1.f/3.f));
      x.w = elu1(x.w + (up.w + us.w + ug.w)*(1.f/3.f));
      *(float4*)&op_out[(size_t)d*64 + h0] = x;
      xkeep = x;
      if (l < 5) {
        atomicAdd(&mop[h0+0], x.x);
        atomicAdd(&mop[h0+1], x.y);
        atomicAdd(&mop[h0+2], x.z);
        atomicAdd(&mop[h0+3], x.w);
        __syncthreads();
        if (tid < 64) ws[O_MOPP + wpar*16384 + (bid-4)*64 + tid] = mop[tid];
      }
    } else {
      // ---------------- task update: 16 tasks ----------------
      float* sTask  = smem;            // 4096
      float* sW0    = smem + 4096;     // 4608
      float* sWe3   = smem + 8704;     // 512
      float* vpl    = smem + 9216;     // 256
      float* mo4    = smem + 9472;     // 256
      float* sums_l = smem + 9728;     // 16*68
      float* sGB0   = smem + 10816;    // 64
      float* sefl   = smem + 10880;    // 128
      float* sefpl  = smem + 11008;    // 128
      float* mtp    = smem + 11136;    // 64
      int* idxl_s   = (int*)(smem + 11200);  // 1024
      int* cl_s     = (int*)(smem + 12224);  // 16

      const int tbase = bid*16;
      const float* gWlink  = gW + (size_t)(l*72)*64;
      const float* gWplace = gW + (size_t)((18 + l)*72)*64;

      // op-partial reduce first (longest latency), ILP-8
      {
        const int col = tid & 63, g = tid >> 6;
        const float* mopp = ws + O_MOPP + rpar*16384;
        float a0=0.f,a1=0.f,a2=0.f,a3=0.f,a4=0.f,a5=0.f,a6=0.f,a7=0.f;
        for (int k = 0; k < 64; k += 8) {
          a0 += mopp[(g + 4*(k+0))*64 + col];
          a1 += mopp[(g + 4*(k+1))*64 + col];
          a2 += mopp[(g + 4*(k+2))*64 + col];
          a3 += mopp[(g + 4*(k+3))*64 + col];
          a4 += mopp[(g + 4*(k+4))*64 + col];
          a5 += mopp[(g + 4*(k+5))*64 + col];
          a6 += mopp[(g + 4*(k+6))*64 + col];
          a7 += mopp[(g + 4*(k+7))*64 + col];
        }
        mo4[g*64 + col] = ((a0+a1)+(a2+a3))+((a4+a5)+(a6+a7));
      }
      for (int i = tid*4; i < 4096; i += 1024)
        *(float4*)&sTask[i] = *(const float4*)&task_in[i];
      for (int i = tid*4; i < 4608; i += 1024)
        *(float4*)&sW0[i] = *(const float4*)&gWlink[i];
      if (tid*4 < 512) *(float4*)&sWe3[tid*4] = *(const float4*)&gWplace[4096 + tid*4];
      if (tid < 16) cl_s[tid] = ib[O_CNT_LINK + tbase + tid];
      for (int i = tid; i < 16*CAP; i += 256) {
        const int t = i >> 6, j = i & 63;
        if (j < ib[O_CNT_LINK + tbase + t]) idxl_s[i] = ib[O_CSRP_LINK + (tbase+t)*CAP + j];
      }
      if (tid < 64) { sGB0[tid] = gb[l*64 + tid]; mtp[tid] = 0.f; }
      if (tid < 128) sefl[tid] = ws[O_SEF_LINK + tbase*8 + tid];
      else sefpl[tid - 128] = ws[O_SEF_PLACE + tbase*8 + (tid - 128)];
      __syncthreads();
      {
        const int col = tid & 63, g = tid >> 6;
        float acc = (g == 0) ? gb[(18+l)*64 + col] : 0.f;
        for (int kk = 0; kk < 16; ++kk) {
          const int k = g*16 + kk;
          const float mok = (mo4[k] + mo4[64+k]) + (mo4[128+k] + mo4[192+k]);
          acc = fmaf(mok*(1.f/4096.f), gWplace[k*64 + col], acc);
        }
        vpl[g*64 + col] = acc;
      }
      __syncthreads();

      const int wv = tid >> 6, lane = tid & 63;
      for (int tt = 0; tt < 4; ++tt) {
        const int t = wv*4 + tt;
        const int pe = min(cl_s[t], CAP);
        float s0=0.f,s1=0.f,s2=0.f,s3=0.f;
        int p = 0;
        for (; p+3 < pe; p += 4) {
          s0 += sTask[idxl_s[t*CAP+p  ]*64 + lane];
          s1 += sTask[idxl_s[t*CAP+p+1]*64 + lane];
          s2 += sTask[idxl_s[t*CAP+p+2]*64 + lane];
          s3 += sTask[idxl_s[t*CAP+p+3]*64 + lane];
        }
        for (; p < pe; ++p) s0 += sTask[idxl_s[t*CAP+p]*64 + lane];
        sums_l[t*68 + lane] = (s0+s1)+(s2+s3);
      }

      const int tL = tid >> 4, h0 = (tid & 15)*4;
      const int tG = tbase + tL;
      float4 ul = make_float4(0.f,0.f,0.f,0.f);
      const int cl2 = cl_s[tL];
      if (cl2 > 0) {
        float4 a = make_float4(0.f,0.f,0.f,0.f);
        for (int k = 0; k < 64; ++k)
          fma4(a, sums_l[tL*68 + k], *(const float4*)&sW0[k*64 + h0]);
#pragma unroll
        for (int cc = 0; cc < 8; ++cc)
          fma4(a, sefl[tL*8 + cc], *(const float4*)&sW0[4096 + cc*64 + h0]);
        const float r = 1.f/(float)cl2;
        ul.x = fmaf(a.x, r, sGB0[h0+0]);
        ul.y = fmaf(a.y, r, sGB0[h0+1]);
        ul.z = fmaf(a.z, r, sGB0[h0+2]);
        ul.w = fmaf(a.w, r, sGB0[h0+3]);
      }
      float4 uq;
      {
        const float4 v0 = *(const float4*)&vpl[h0];
        const float4 v1 = *(const float4*)&vpl[64 + h0];
        const float4 v2 = *(const float4*)&vpl[128 + h0];
        const float4 v3 = *(const float4*)&vpl[192 + h0];
        uq.x = (v0.x+v1.x)+(v2.x+v3.x);
        uq.y = (v0.y+v1.y)+(v2.y+v3.y);
        uq.z = (v0.z+v1.z)+(v2.z+v3.z);
        uq.w = (v0.w+v1.w)+(v2.w+v3.w);
#pragma unroll
        for (int cc = 0; cc < 8; ++cc)
          fma4(uq, sefpl[tL*8 + cc]*(1.f/4096.f), *(const float4*)&sWe3[cc*64 + h0]);
      }
      float4 x = *(const float4*)&sTask[tG*64 + h0];
      x.x = elu1(x.x + (ul.x + uq.x)*0.5f);
      x.y = elu1(x.y + (ul.y + uq.y)*0.5f);
      x.z = elu1(x.z + (ul.z + uq.z)*0.5f);
      x.w = elu1(x.w + (ul.w + uq.w)*0.5f);
      *(float4*)&task_out[(size_t)tG*64 + h0] = x;
      if (l < 5) {
        atomicAdd(&mtp[h0+0], x.x);
        atomicAdd(&mtp[h0+1], x.y);
        atomicAdd(&mtp[h0+2], x.z);
        atomicAdd(&mtp[h0+3], x.w);
        __syncthreads();
        if (tid < 64) ws[O_MTPP + wpar*256 + bid*64 + tid] = mtp[tid];
      }
    }
    gridbar(bar);
  }

  // ---- finale: out[i,t] = a_i + b_e + c_t + bias (op rows live in xkeep regs) ----
  if (bid >= 4) {
    const int obase = (bid - 4)*16;
    float* sT   = smem;          // 4096
    float* cvp  = smem + 4096;   // 256
    float* cvec = smem + 4352;   // 64
    for (int i = tid*4; i < 4096; i += 1024)
      *(float4*)&sT[i] = *(const float4*)&ws[O_TASK_A + i];
    __syncthreads();
    {
      const int t = tid & 63, g = tid >> 6;
      float p = 0.f;
      for (int kk = 0; kk < 16; ++kk) {
        const int k = g*16 + kk;
        p = fmaf(sT[t*64 + k], finalW[72 + k], p);
      }
      cvp[g*64 + t] = p;
    }
    __syncthreads();
    if (tid < 64) cvec[tid] = (cvp[tid] + cvp[64+tid]) + (cvp[128+tid] + cvp[192+tid]);
    __syncthreads();
    const int oL = tid >> 4, h0 = (tid & 15)*4;
    const int d = obase + oL;
    const float4 fw = *(const float4*)&finalW[h0];
    float av = xkeep.x*fw.x + xkeep.y*fw.y + xkeep.z*fw.z + xkeep.w*fw.w;
    av += __shfl_xor(av, 1, 64);
    av += __shfl_xor(av, 2, 64);
    av += __shfl_xor(av, 4, 64);
    av += __shfl_xor(av, 8, 64);
    const float fb = finalb[0];
    const float4 bp = *(const float4*)&ws[O_BPLACE + (size_t)d*64 + h0];
    float4 o4;
    o4.x = av + bp.x + cvec[h0+0] + fb;
    o4.y = av + bp.y + cvec[h0+1] + fb;
    o4.z = av + bp.z + cvec[h0+2] + fb;
    o4.w = av + bp.w + cvec[h0+3] + fb;
    *(float4*)&out[(size_t)d*64 + h0] = o4;
  }
}

extern "C" void kernel_launch(void* const* d_in, const int* in_sizes, int n_in,
                              void* d_out, int out_size, void* d_ws, size_t ws_size,
                              hipStream_t stream)
{
  (void)in_sizes; (void)n_in; (void)out_size;
  if (ws_size < (size_t)O_TOTAL * sizeof(float)) return;

  const float* op_feats     = (const float*)d_in[0];
  const float* task_feats   = (const float*)d_in[1];
  const float* tensor_feats = (const float*)d_in[2];
  const float* link_feats   = (const float*)d_in[3];
  const float* place_feats  = (const float*)d_in[4];
  const int*   prev_src     = (const int*)d_in[5];
  const int*   prev_dst     = (const int*)d_in[6];
  const int*   link_src     = (const int*)d_in[7];
  const int*   link_dst     = (const int*)d_in[8];
  const float* op_W         = (const float*)d_in[9];
  const float* op_b         = (const float*)d_in[10];
  const float* task_W       = (const float*)d_in[11];
  const float* task_b       = (const float*)d_in[12];
  const float* eW           = (const float*)d_in[13];
  const float* eb           = (const float*)d_in[14];
  const float* gW           = (const float*)d_in[15];
  const float* gb           = (const float*)d_in[16];
  const float* finalW       = (const float*)d_in[17];
  const float* finalb       = (const float*)d_in[18];
  float* w = (float*)d_ws;
  float* out = (float*)d_out;

  k_embed<<<257, 256, 0, stream>>>(op_feats, op_W, op_b, task_feats, task_W, task_b, w);
  k_edge_place<<<384, 256, 0, stream>>>(tensor_feats, link_feats, place_feats,
                                        prev_src, prev_dst, link_src, link_dst,
                                        eW, eb, finalW, w);
  k_mega<<<NBLK, 256, 0, stream>>>(gW, gb, finalW, finalb, w, out);
}

// Round 5
// 194.862 us; speedup vs baseline: 2.3277x; 2.3277x over previous
//
#include <hip/hip_runtime.h>
#include <math.h>

#define NOP 4096
#define NTASK 64
#define NTENSOR 32768
#define NLINK 1024
#define NPLACE (NOP*NTASK)
#define CAP 64
#define NOPB 512          // op-update blocks (8 ops each)

// ---- workspace layout (units of 4 bytes) ----
enum : int {
  O_CNT_PREV  = 0,                          // 4096 ints
  O_CNT_SUCC  = O_CNT_PREV + NOP,
  O_CNT_LINK  = O_CNT_SUCC + NOP,           // 64
  O_SEF_PREV  = O_CNT_LINK + 64,            // NOP*8
  O_SEF_SUCC  = O_SEF_PREV + NOP*8,
  O_SEF_LINK  = O_SEF_SUCC + NOP*8,         // 64*8
  O_SEF_PLACE = O_SEF_LINK + 64*8,          // 64*8
  O_SEF_SERVE = O_SEF_PLACE + 64*8,         // NOP*8
  O_OP_A      = O_SEF_SERVE + NOP*8,        // NOP*64
  O_OP_B      = O_OP_A + NOP*64,
  O_TASK_A    = O_OP_B + NOP*64,            // 64*64
  O_TASK_B    = O_TASK_A + 64*64,
  O_BPLACE    = O_TASK_B + 64*64,           // NPLACE
  O_AOP       = O_BPLACE + NPLACE,          // NOP
  O_CVEC      = O_AOP + NOP,                // 64
  O_MOPP      = O_CVEC + 64,                // 2 * 512*64
  O_MTPP      = O_MOPP + 2*512*64,          // 2 * 4*64
  O_SPLP      = O_MTPP + 2*4*64,            // 256*512
  O_CSRP_PREV = O_SPLP + 256*512,           // NOP*CAP ints
  O_CSRP_SUCC = O_CSRP_PREV + NOP*CAP,
  O_CSRP_LINK = O_CSRP_SUCC + NOP*CAP,      // 64*CAP
  O_EFS_PREV  = O_CSRP_LINK + 64*CAP,       // NOP*CAP*8 floats
  O_EFS_SUCC  = O_EFS_PREV + NOP*CAP*8,
  O_EFS_LINK  = O_EFS_SUCC + NOP*CAP*8,     // 64*CAP*8
  O_TOTAL     = O_EFS_LINK + 64*CAP*8
};

__device__ __forceinline__ float elu1(float x) { return x > 0.f ? x : expm1f(x); }

__device__ __forceinline__ void fma4(float4& a, const float s, const float4 w) {
  a.x = fmaf(s, w.x, a.x);
  a.y = fmaf(s, w.y, a.y);
  a.z = fmaf(s, w.z, a.z);
  a.w = fmaf(s, w.w, a.w);
}

// ---------------- embeddings (blocks 0..255: ops; block 256: tasks + zeroing) ----------------
__global__ __launch_bounds__(256) void k_embed(
    const float* __restrict__ opA, const float* __restrict__ opW, const float* __restrict__ opb,
    const float* __restrict__ taskA, const float* __restrict__ taskW, const float* __restrict__ taskb,
    float* __restrict__ ws)
{
  const int tid = threadIdx.x;
  const int bid = blockIdx.x;
  if (bid < 256) {
    __shared__ float sW[8192];
    __shared__ float sA[16*260];
    __shared__ float4 red[256];
    const int obase = bid * 16;
    for (int i = tid; i < 4096; i += 256) {
      const int o = i >> 8, k = i & 255;
      sA[o*260 + k] = opA[(size_t)(obase + o)*256 + k];
    }
    const int o = tid >> 4, hq = tid & 15, h0 = hq*4;
    float4 acc = *(const float4*)&opb[h0];
    for (int half = 0; half < 2; ++half) {
      __syncthreads();
      for (int i = tid*4; i < 8192; i += 1024)
        *(float4*)&sW[i] = *(const float4*)&opW[half*8192 + i];
      __syncthreads();
      const float* a = &sA[o*260 + half*128];
      for (int k = 0; k < 128; ++k)
        fma4(acc, a[k], *(const float4*)&sW[k*64 + h0]);
    }
    acc.x = elu1(acc.x); acc.y = elu1(acc.y); acc.z = elu1(acc.z); acc.w = elu1(acc.w);
    *(float4*)&ws[O_OP_A + (size_t)(obase + o)*64 + h0] = acc;
    red[tid] = acc;
    __syncthreads();
    if (tid < 16) {
      float4 s = make_float4(0.f,0.f,0.f,0.f);
      for (int g = 0; g < 16; ++g) {
        float4 v = red[g*16 + tid];
        s.x += v.x; s.y += v.y; s.z += v.z; s.w += v.w;
      }
      *(float4*)&ws[O_MOPP + bid*64 + tid*4] = s;   // parity-0 slot
    }
  } else {
    __shared__ float sA[64*65];
    __shared__ float sW[64*64];
    __shared__ float4 red[256];
    int* ib = (int*)ws;
    for (int i = tid; i < NOP*2 + 64; i += 256) ib[O_CNT_PREV + i] = 0;
    for (int i = tid; i < 4096; i += 256) {
      const int t = i >> 6, k = i & 63;
      sA[t*65 + k] = taskA[i];
    }
    for (int i = tid*4; i < 4096; i += 1024)
      *(float4*)&sW[i] = *(const float4*)&taskW[i];
    __syncthreads();
    const int og = tid >> 4, hq = tid & 15, h0 = hq*4;
    float4 msum = make_float4(0.f,0.f,0.f,0.f);
    for (int tg = 0; tg < 4; ++tg) {
      const int t = tg*16 + og;
      float4 acc = *(const float4*)&taskb[h0];
      const float* a = &sA[t*65];
      for (int k = 0; k < 64; ++k)
        fma4(acc, a[k], *(const float4*)&sW[k*64 + h0]);
      acc.x = elu1(acc.x); acc.y = elu1(acc.y); acc.z = elu1(acc.z); acc.w = elu1(acc.w);
      *(float4*)&ws[O_TASK_A + t*64 + h0] = acc;
      msum.x += acc.x; msum.y += acc.y; msum.z += acc.z; msum.w += acc.w;
    }
    red[tid] = msum;
    __syncthreads();
    if (tid < 16) {
      float4 s = make_float4(0.f,0.f,0.f,0.f);
      for (int g = 0; g < 16; ++g) {
        float4 v = red[g*16 + tid];
        s.x += v.x; s.y += v.y; s.z += v.z; s.w += v.w;
      }
      *(float4*)&ws[O_MTPP + tid*4] = s;   // parity-0, slot 0
    }
  }
}

// -------- edges (blocks 0..127) + place/serve (blocks 128..383) --------
__global__ __launch_bounds__(256) void k_edge_place(
    const float* __restrict__ tensor_feats, const float* __restrict__ link_feats,
    const float* __restrict__ place_feats,
    const int* __restrict__ prev_src, const int* __restrict__ prev_dst,
    const int* __restrict__ link_src, const int* __restrict__ link_dst,
    const float* __restrict__ eW, const float* __restrict__ eb,
    const float* __restrict__ finalW, float* __restrict__ ws)
{
  const int tid = threadIdx.x;
  const int bid = blockIdx.x;
  int* ib = (int*)ws;
  if (bid < 128) {
    __shared__ float sEW[384];
    __shared__ float sEB[24];
    for (int i = tid; i < 384; i += 256) sEW[i] = eW[i];
    if (tid < 24) sEB[tid] = eb[tid];
    __syncthreads();
    const int e = bid*256 + tid;
    float raw[16];
    *(float4*)&raw[0]  = *(const float4*)&tensor_feats[(size_t)e*16 + 0];
    *(float4*)&raw[4]  = *(const float4*)&tensor_feats[(size_t)e*16 + 4];
    *(float4*)&raw[8]  = *(const float4*)&tensor_feats[(size_t)e*16 + 8];
    *(float4*)&raw[12] = *(const float4*)&tensor_feats[(size_t)e*16 + 12];
    float efp[8], efs[8];
#pragma unroll
    for (int c = 0; c < 8; ++c) { efp[c] = sEB[8+c]; efs[c] = sEB[16+c]; }
#pragma unroll
    for (int k = 0; k < 16; ++k) {
      const float a = raw[k];
#pragma unroll
      for (int c = 0; c < 8; ++c) {
        efp[c] = fmaf(a, sEW[128 + k*8 + c], efp[c]);
        efs[c] = fmaf(a, sEW[256 + k*8 + c], efs[c]);
      }
    }
#pragma unroll
    for (int c = 0; c < 8; ++c) { efp[c] = elu1(efp[c]); efs[c] = elu1(efs[c]); }
    const int pd = prev_dst[e], ps = prev_src[e];
    {
      int pos = atomicAdd(&ib[O_CNT_PREV + pd], 1);
      if (pos < CAP) {
        ib[O_CSRP_PREV + pd*CAP + pos] = ps;
        float* dst = ws + O_EFS_PREV + ((size_t)pd*CAP + pos)*8;
        *(float4*)&dst[0] = make_float4(efp[0],efp[1],efp[2],efp[3]);
        *(float4*)&dst[4] = make_float4(efp[4],efp[5],efp[6],efp[7]);
      }
    }
    {
      int pos = atomicAdd(&ib[O_CNT_SUCC + ps], 1);
      if (pos < CAP) {
        ib[O_CSRP_SUCC + ps*CAP + pos] = pd;
        float* dst = ws + O_EFS_SUCC + ((size_t)ps*CAP + pos)*8;
        *(float4*)&dst[0] = make_float4(efs[0],efs[1],efs[2],efs[3]);
        *(float4*)&dst[4] = make_float4(efs[4],efs[5],efs[6],efs[7]);
      }
    }
    if (e < NLINK) {
      float rl[16];
      *(float4*)&rl[0]  = *(const float4*)&link_feats[(size_t)e*16 + 0];
      *(float4*)&rl[4]  = *(const float4*)&link_feats[(size_t)e*16 + 4];
      *(float4*)&rl[8]  = *(const float4*)&link_feats[(size_t)e*16 + 8];
      *(float4*)&rl[12] = *(const float4*)&link_feats[(size_t)e*16 + 12];
      float efl[8];
#pragma unroll
      for (int c = 0; c < 8; ++c) efl[c] = sEB[c];
#pragma unroll
      for (int k = 0; k < 16; ++k) {
        const float a = rl[k];
#pragma unroll
        for (int c = 0; c < 8; ++c) efl[c] = fmaf(a, sEW[k*8 + c], efl[c]);
      }
      const int ld = link_dst[e];
      int pos = atomicAdd(&ib[O_CNT_LINK + ld], 1);
      if (pos < CAP) {
        ib[O_CSRP_LINK + ld*CAP + pos] = link_src[e];
        float* dst = ws + O_EFS_LINK + ((size_t)ld*CAP + pos)*8;
        *(float4*)&dst[0] = make_float4(elu1(efl[0]),elu1(efl[1]),elu1(efl[2]),elu1(efl[3]));
        *(float4*)&dst[4] = make_float4(elu1(efl[4]),elu1(efl[5]),elu1(efl[6]),elu1(efl[7]));
      }
    }
  } else {
    __shared__ float sW3[128], sW4[128], sB3[8], sB4[8], sW1[8];
    __shared__ float pl[512];
    const int pbid = bid - 128;
    if (tid < 128) { sW3[tid] = eW[3*128 + tid]; sW4[tid] = eW[4*128 + tid]; }
    if (tid < 8) { sB3[tid] = eb[24+tid]; sB4[tid] = eb[32+tid]; sW1[tid] = finalW[64+tid]; }
    for (int i = tid; i < 512; i += 256) pl[i] = 0.f;
    __syncthreads();
    const int lane = tid & 63;
    const int wave = (pbid*256 + tid) >> 6;   // 0..1023, 4 op-rows each
    float pacc[8];
#pragma unroll
    for (int c = 0; c < 8; ++c) pacc[c] = 0.f;
    float* bplace = ws + O_BPLACE;
    float* sserve = ws + O_SEF_SERVE;
    for (int j = 0; j < 4; ++j) {
      const int i = wave*4 + j;
      const int e = i*64 + lane;
      float raw[16];
      *(float4*)&raw[0]  = *(const float4*)&place_feats[(size_t)e*16 + 0];
      *(float4*)&raw[4]  = *(const float4*)&place_feats[(size_t)e*16 + 4];
      *(float4*)&raw[8]  = *(const float4*)&place_feats[(size_t)e*16 + 8];
      *(float4*)&raw[12] = *(const float4*)&place_feats[(size_t)e*16 + 12];
      float efp[8], efs[8];
#pragma unroll
      for (int c = 0; c < 8; ++c) { efp[c] = sB3[c]; efs[c] = sB4[c]; }
#pragma unroll
      for (int k = 0; k < 16; ++k) {
        const float a = raw[k];
#pragma unroll
        for (int c = 0; c < 8; ++c) {
          efp[c] = fmaf(a, sW3[k*8 + c], efp[c]);
          efs[c] = fmaf(a, sW4[k*8 + c], efs[c]);
        }
      }
      float bp = 0.f;
#pragma unroll
      for (int c = 0; c < 8; ++c) {
        efp[c] = elu1(efp[c]);
        efs[c] = elu1(efs[c]);
        bp = fmaf(efp[c], sW1[c], bp);
        pacc[c] += efp[c];
      }
      bplace[e] = bp;
#pragma unroll
      for (int c = 0; c < 8; ++c) {
        float v = efs[c];
        for (int m = 32; m >= 1; m >>= 1) v += __shfl_xor(v, m, 64);
        if (lane == 0) sserve[i*8 + c] = v;
      }
    }
#pragma unroll
    for (int c = 0; c < 8; ++c) atomicAdd(&pl[lane*8 + c], pacc[c]);
    __syncthreads();
    for (int i = tid; i < 512; i += 256) ws[O_SPLP + pbid*512 + i] = pl[i];
  }
}

// ------------- one GNN layer (l==0 computes SEF sums; l==5 computes final dots) -------------
__global__ __launch_bounds__(256) void k_layer(
    const int l,
    const float* __restrict__ gW, const float* __restrict__ gb,
    const float* __restrict__ finalW,
    const float* __restrict__ op_in, float* __restrict__ op_out,
    const float* __restrict__ task_in, float* __restrict__ task_out,
    float* __restrict__ ws)
{
  __shared__ float smem[12544];
  const int tid = threadIdx.x;
  const int bid = blockIdx.x;
  const int* ib = (const int*)ws;
  const int rpar = l & 1, wpar = 1 - rpar;

  if (bid < NOPB) {
    // ---------------- op update: 8 ops ----------------
    float* sWp    = smem;            // 4608
    float* sWs    = smem + 4608;     // 4608
    float* sWeS   = smem + 9216;     // 512
    float* vp     = smem + 9728;     // 256
    float* sums_p = smem + 9984;     // 8*68
    float* sums_s = smem + 10528;    // 8*68
    float* sGB    = smem + 11072;    // 128
    float* sef    = smem + 11200;    // 192
    float* mop    = smem + 11392;    // 64
    int* idxp_s   = (int*)(smem + 11456);  // 512
    int* idxs_s   = (int*)(smem + 11968);  // 512
    int* cp_s     = (int*)(smem + 12480);  // 8
    int* cs_s     = (int*)(smem + 12488);  // 8

    const int obase = bid*8;
    const float* gWprev  = gW + (size_t)((6  + l)*72)*64;
    const float* gWsucc  = gW + (size_t)((12 + l)*72)*64;
    const float* gWserve = gW + (size_t)((24 + l)*72)*64;

    for (int i = tid*4; i < 4608; i += 1024) {
      *(float4*)&sWp[i] = *(const float4*)&gWprev[i];
      *(float4*)&sWs[i] = *(const float4*)&gWsucc[i];
    }
    if (tid*4 < 512) *(float4*)&sWeS[tid*4] = *(const float4*)&gWserve[4096 + tid*4];
    if (tid < 8) cp_s[tid] = ib[O_CNT_PREV + obase + tid];
    else if (tid < 16) cs_s[tid-8] = ib[O_CNT_SUCC + obase + (tid-8)];
    for (int i = tid; i < 8*CAP; i += 256) {
      const int o = i >> 6, j = i & 63;
      if (j < ib[O_CNT_PREV + obase + o]) idxp_s[i] = ib[O_CSRP_PREV + (obase+o)*CAP + j];
      if (j < ib[O_CNT_SUCC + obase + o]) idxs_s[i] = ib[O_CSRP_SUCC + (obase+o)*CAP + j];
    }
    if (tid < 128) sGB[tid] = (tid < 64) ? gb[(6+l)*64 + tid] : gb[(12+l)*64 + (tid-64)];
    if (tid < 64) mop[tid] = 0.f;
    if (l == 0) {
      if (tid < 128) {
        const bool isP = (tid < 64);
        const int t2 = tid & 63;
        const int o = t2 >> 3, c = t2 & 7;
        const int cnt = min(ib[(isP ? O_CNT_PREV : O_CNT_SUCC) + obase + o], CAP);
        const float* efs = ws + (isP ? O_EFS_PREV : O_EFS_SUCC) + ((size_t)(obase+o)*CAP)*8;
        float s0 = 0.f, s1 = 0.f;
        int j = 0;
        for (; j+1 < cnt; j += 2) { s0 += efs[j*8+c]; s1 += efs[j*8+8+c]; }
        if (j < cnt) s0 += efs[j*8+c];
        const float s = s0 + s1;
        sef[tid] = s;
        ws[(isP ? O_SEF_PREV : O_SEF_SUCC) + obase*8 + t2] = s;
      } else if (tid < 192) {
        sef[tid] = ws[O_SEF_SERVE + obase*8 + (tid-128)];
      }
    } else {
      if (tid < 64)       sef[tid] = ws[O_SEF_PREV + obase*8 + tid];
      else if (tid < 128) sef[tid] = ws[O_SEF_SUCC + obase*8 + (tid-64)];
      else if (tid < 192) sef[tid] = ws[O_SEF_SERVE + obase*8 + (tid-128)];
    }
    {
      // vserve partials from task-sum partials
      const int col = tid & 63, g = tid >> 6;
      const float* mtpp = ws + O_MTPP + rpar*256;
      const int nst = (l == 0) ? 1 : 4;
      float acc = (g == 0) ? gb[(24+l)*64 + col] : 0.f;
      for (int kk = 0; kk < 16; ++kk) {
        const int k = g*16 + kk;
        float mt = 0.f;
        for (int s = 0; s < nst; ++s) mt += mtpp[s*64 + k];
        acc = fmaf(mt*(1.f/64.f), gWserve[k*64 + col], acc);
      }
      vp[g*64 + col] = acc;
    }
    __syncthreads();

    // --- per-wave gather (wave-local: wave wv owns ops 2wv, 2wv+1) ---
    const int wv = tid >> 6, lane = tid & 63;
#pragma unroll
    for (int oo = 0; oo < 2; ++oo) {
      const int o = 2*wv + oo;
      {
        const int pe = min(cp_s[o], CAP);
        float s0=0.f,s1=0.f,s2=0.f,s3=0.f;
        int p = 0;
        for (; p+3 < pe; p += 4) {
          s0 += op_in[(size_t)idxp_s[o*CAP+p  ]*64 + lane];
          s1 += op_in[(size_t)idxp_s[o*CAP+p+1]*64 + lane];
          s2 += op_in[(size_t)idxp_s[o*CAP+p+2]*64 + lane];
          s3 += op_in[(size_t)idxp_s[o*CAP+p+3]*64 + lane];
        }
        for (; p < pe; ++p) s0 += op_in[(size_t)idxp_s[o*CAP+p]*64 + lane];
        sums_p[o*68 + lane] = (s0+s1)+(s2+s3);
      }
      {
        const int pe = min(cs_s[o], CAP);
        float s0=0.f,s1=0.f,s2=0.f,s3=0.f;
        int p = 0;
        for (; p+3 < pe; p += 4) {
          s0 += op_in[(size_t)idxs_s[o*CAP+p  ]*64 + lane];
          s1 += op_in[(size_t)idxs_s[o*CAP+p+1]*64 + lane];
          s2 += op_in[(size_t)idxs_s[o*CAP+p+2]*64 + lane];
          s3 += op_in[(size_t)idxs_s[o*CAP+p+3]*64 + lane];
        }
        for (; p < pe; ++p) s0 += op_in[(size_t)idxs_s[o*CAP+p]*64 + lane];
        sums_s[o*68 + lane] = (s0+s1)+(s2+s3);
      }
    }

    // --- matmul: thread -> (op tid>>5, cols c,c+1) ---
    const int oL = tid >> 5, c = (tid & 31)*2;
    const int d  = obase + oL;
    float up0 = 0.f, up1 = 0.f, us0 = 0.f, us1 = 0.f;
    const int cp = cp_s[oL];
    if (cp > 0) {
      float a0 = 0.f, a1 = 0.f;
      for (int k = 0; k < 64; ++k) {
        const float sk = sums_p[oL*68 + k];
        const float2 wv2 = *(const float2*)&sWp[k*64 + c];
        a0 = fmaf(sk, wv2.x, a0);
        a1 = fmaf(sk, wv2.y, a1);
      }
#pragma unroll
      for (int cc = 0; cc < 8; ++cc) {
        const float ev = sef[oL*8 + cc];
        const float2 wv2 = *(const float2*)&sWp[4096 + cc*64 + c];
        a0 = fmaf(ev, wv2.x, a0);
        a1 = fmaf(ev, wv2.y, a1);
      }
      const float r = 1.f/(float)cp;
      up0 = fmaf(a0, r, sGB[c]);
      up1 = fmaf(a1, r, sGB[c+1]);
    }
    const int cs = cs_s[oL];
    if (cs > 0) {
      float a0 = 0.f, a1 = 0.f;
      for (int k = 0; k < 64; ++k) {
        const float sk = sums_s[oL*68 + k];
        const float2 wv2 = *(const float2*)&sWs[k*64 + c];
        a0 = fmaf(sk, wv2.x, a0);
        a1 = fmaf(sk, wv2.y, a1);
      }
#pragma unroll
      for (int cc = 0; cc < 8; ++cc) {
        const float ev = sef[64 + oL*8 + cc];
        const float2 wv2 = *(const float2*)&sWs[4096 + cc*64 + c];
        a0 = fmaf(ev, wv2.x, a0);
        a1 = fmaf(ev, wv2.y, a1);
      }
      const float r = 1.f/(float)cs;
      us0 = fmaf(a0, r, sGB[64 + c]);
      us1 = fmaf(a1, r, sGB[64 + c + 1]);
    }
    float g0, g1;
    {
      const float2 v0 = *(const float2*)&vp[c];
      const float2 v1 = *(const float2*)&vp[64 + c];
      const float2 v2 = *(const float2*)&vp[128 + c];
      const float2 v3 = *(const float2*)&vp[192 + c];
      g0 = (v0.x + v1.x) + (v2.x + v3.x);
      g1 = (v0.y + v1.y) + (v2.y + v3.y);
#pragma unroll
      for (int cc = 0; cc < 8; ++cc) {
        const float ev = sef[128 + oL*8 + cc] * (1.f/64.f);
        const float2 wv2 = *(const float2*)&sWeS[cc*64 + c];
        g0 = fmaf(ev, wv2.x, g0);
        g1 = fmaf(ev, wv2.y, g1);
      }
    }
    const float2 x = *(const float2*)&op_in[(size_t)d*64 + c];
    const float r0 = elu1(x.x + (up0 + us0 + g0)*(1.f/3.f));
    const float r1 = elu1(x.y + (up1 + us1 + g1)*(1.f/3.f));
    if (l < 5) {
      float2 xo; xo.x = r0; xo.y = r1;
      *(float2*)&op_out[(size_t)d*64 + c] = xo;
      atomicAdd(&mop[c],   r0);
      atomicAdd(&mop[c+1], r1);
      __syncthreads();
      if (tid < 64) ws[O_MOPP + wpar*32768 + bid*64 + tid] = mop[tid];
    } else {
      // final a_i = dot(op_row, finalW[0:64]) via 32-lane reduce
      float av = r0*finalW[c] + r1*finalW[c+1];
      av += __shfl_xor(av, 1, 64);
      av += __shfl_xor(av, 2, 64);
      av += __shfl_xor(av, 4, 64);
      av += __shfl_xor(av, 8, 64);
      av += __shfl_xor(av, 16, 64);
      if ((tid & 31) == 0) ws[O_AOP + d] = av;
    }
  } else {
    // ---------------- task update: 16 tasks (4 blocks) ----------------
    const int tbase = (bid - NOPB)*16;
    float* sTask  = smem;            // 4096
    float* sW0    = smem + 4096;     // 4608
    float* sWe3   = smem + 8704;     // 512
    float* vpl    = smem + 9216;     // 256
    float* mo4    = smem + 9472;     // 256
    float* sums_l = smem + 9728;     // 16*68
    float* sGB0   = smem + 10816;    // 64
    float* sefl   = smem + 10880;    // 128
    float* sefpl  = smem + 11008;    // 128
    float* mtp    = smem + 11136;    // 64
    int* idxl_s   = (int*)(smem + 11200);  // 1024
    int* cl_s     = (int*)(smem + 12224);  // 16

    const float* gWlink  = gW + (size_t)(l*72)*64;
    const float* gWplace = gW + (size_t)((18 + l)*72)*64;

    // op-partial reduce (nso slots), ILP-8
    {
      const int col = tid & 63, g = tid >> 6;
      const float* mopp = ws + O_MOPP + rpar*32768;
      const int nso = (l == 0) ? 256 : 512;
      float a0=0.f,a1=0.f,a2=0.f,a3=0.f,a4=0.f,a5=0.f,a6=0.f,a7=0.f;
      for (int s = g; s < nso; s += 32) {
        a0 += mopp[(s+0 )*64 + col];
        a1 += mopp[(s+4 )*64 + col];
        a2 += mopp[(s+8 )*64 + col];
        a3 += mopp[(s+12)*64 + col];
        a4 += mopp[(s+16)*64 + col];
        a5 += mopp[(s+20)*64 + col];
        a6 += mopp[(s+24)*64 + col];
        a7 += mopp[(s+28)*64 + col];
      }
      mo4[g*64 + col] = ((a0+a1)+(a2+a3)) + ((a4+a5)+(a6+a7));
    }
    for (int i = tid*4; i < 4096; i += 1024)
      *(float4*)&sTask[i] = *(const float4*)&task_in[i];
    for (int i = tid*4; i < 4608; i += 1024)
      *(float4*)&sW0[i] = *(const float4*)&gWlink[i];
    if (tid*4 < 512) *(float4*)&sWe3[tid*4] = *(const float4*)&gWplace[4096 + tid*4];
    if (tid < 16) cl_s[tid] = ib[O_CNT_LINK + tbase + tid];
    for (int i = tid; i < 16*CAP; i += 256) {
      const int t = i >> 6, j = i & 63;
      if (j < ib[O_CNT_LINK + tbase + t]) idxl_s[i] = ib[O_CSRP_LINK + (tbase+t)*CAP + j];
    }
    if (tid < 64) { sGB0[tid] = gb[l*64 + tid]; mtp[tid] = 0.f; }
    if (l == 0) {
      if (tid < 128) {
        const int t = tid >> 3, c = tid & 7;
        const int cnt = min(ib[O_CNT_LINK + tbase + t], CAP);
        const float* efs = ws + O_EFS_LINK + ((size_t)(tbase+t)*CAP)*8;
        float s0 = 0.f, s1 = 0.f;
        int j = 0;
        for (; j+1 < cnt; j += 2) { s0 += efs[j*8+c]; s1 += efs[j*8+8+c]; }
        if (j < cnt) s0 += efs[j*8+c];
        const float s = s0 + s1;
        sefl[tid] = s;
        ws[O_SEF_LINK + tbase*8 + tid] = s;
      } else {
        const int idx = tid - 128;
        float s0=0.f,s1=0.f,s2=0.f,s3=0.f;
        for (int r = 0; r < 256; r += 4) {
          s0 += ws[O_SPLP + (r+0)*512 + tbase*8 + idx];
          s1 += ws[O_SPLP + (r+1)*512 + tbase*8 + idx];
          s2 += ws[O_SPLP + (r+2)*512 + tbase*8 + idx];
          s3 += ws[O_SPLP + (r+3)*512 + tbase*8 + idx];
        }
        const float s = (s0+s1)+(s2+s3);
        sefpl[idx] = s;
        ws[O_SEF_PLACE + tbase*8 + idx] = s;
      }
    } else {
      if (tid < 128) sefl[tid] = ws[O_SEF_LINK + tbase*8 + tid];
      else sefpl[tid - 128] = ws[O_SEF_PLACE + tbase*8 + (tid - 128)];
    }
    __syncthreads();
    {
      const int col = tid & 63, g = tid >> 6;
      float acc = (g == 0) ? gb[(18+l)*64 + col] : 0.f;
      for (int kk = 0; kk < 16; ++kk) {
        const int k = g*16 + kk;
        const float mok = (mo4[k] + mo4[64+k]) + (mo4[128+k] + mo4[192+k]);
        acc = fmaf(mok*(1.f/4096.f), gWplace[k*64 + col], acc);
      }
      vpl[g*64 + col] = acc;
    }
    __syncthreads();

    const int wv = tid >> 6, lane = tid & 63;
#pragma unroll
    for (int tt = 0; tt < 4; ++tt) {
      const int t = 4*wv + tt;
      const int pe = min(cl_s[t], CAP);
      float s0=0.f,s1=0.f,s2=0.f,s3=0.f;
      int p = 0;
      for (; p+3 < pe; p += 4) {
        s0 += sTask[idxl_s[t*CAP+p  ]*64 + lane];
        s1 += sTask[idxl_s[t*CAP+p+1]*64 + lane];
        s2 += sTask[idxl_s[t*CAP+p+2]*64 + lane];
        s3 += sTask[idxl_s[t*CAP+p+3]*64 + lane];
      }
      for (; p < pe; ++p) s0 += sTask[idxl_s[t*CAP+p]*64 + lane];
      sums_l[t*68 + lane] = (s0+s1)+(s2+s3);
    }

    const int tL = tid >> 4, h0 = (tid & 15)*4;
    const int tG = tbase + tL;
    float4 ul = make_float4(0.f,0.f,0.f,0.f);
    const int cl2 = cl_s[tL];
    if (cl2 > 0) {
      float4 a = make_float4(0.f,0.f,0.f,0.f);
      for (int k = 0; k < 64; ++k)
        fma4(a, sums_l[tL*68 + k], *(const float4*)&sW0[k*64 + h0]);
#pragma unroll
      for (int cc = 0; cc < 8; ++cc)
        fma4(a, sefl[tL*8 + cc], *(const float4*)&sW0[4096 + cc*64 + h0]);
      const float r = 1.f/(float)cl2;
      ul.x = fmaf(a.x, r, sGB0[h0+0]);
      ul.y = fmaf(a.y, r, sGB0[h0+1]);
      ul.z = fmaf(a.z, r, sGB0[h0+2]);
      ul.w = fmaf(a.w, r, sGB0[h0+3]);
    }
    float4 uq;
    {
      const float4 v0 = *(const float4*)&vpl[h0];
      const float4 v1 = *(const float4*)&vpl[64 + h0];
      const float4 v2 = *(const float4*)&vpl[128 + h0];
      const float4 v3 = *(const float4*)&vpl[192 + h0];
      uq.x = (v0.x+v1.x)+(v2.x+v3.x);
      uq.y = (v0.y+v1.y)+(v2.y+v3.y);
      uq.z = (v0.z+v1.z)+(v2.z+v3.z);
      uq.w = (v0.w+v1.w)+(v2.w+v3.w);
#pragma unroll
      for (int cc = 0; cc < 8; ++cc)
        fma4(uq, sefpl[tL*8 + cc]*(1.f/4096.f), *(const float4*)&sWe3[cc*64 + h0]);
    }
    float4 x = *(const float4*)&sTask[tG*64 + h0];
    x.x = elu1(x.x + (ul.x + uq.x)*0.5f);
    x.y = elu1(x.y + (ul.y + uq.y)*0.5f);
    x.z = elu1(x.z + (ul.z + uq.z)*0.5f);
    x.w = elu1(x.w + (ul.w + uq.w)*0.5f);
    if (l < 5) {
      *(float4*)&task_out[(size_t)tG*64 + h0] = x;
      atomicAdd(&mtp[h0+0], x.x);
      atomicAdd(&mtp[h0+1], x.y);
      atomicAdd(&mtp[h0+2], x.z);
      atomicAdd(&mtp[h0+3], x.w);
      __syncthreads();
      if (tid < 64) ws[O_MTPP + wpar*256 + (bid - NOPB)*64 + tid] = mtp[tid];
    } else {
      // final c_t = dot(task_row, finalW[72:136]) via 16-lane reduce
      const float4 fw = *(const float4*)&finalW[72 + h0];
      float cv = x.x*fw.x + x.y*fw.y + x.z*fw.z + x.w*fw.w;
      cv += __shfl_xor(cv, 1, 64);
      cv += __shfl_xor(cv, 2, 64);
      cv += __shfl_xor(cv, 4, 64);
      cv += __shfl_xor(cv, 8, 64);
      if ((tid & 15) == 0) ws[O_CVEC + tG] = cv;
    }
  }
}

// ------------- final head: pure streaming add -------------
__global__ __launch_bounds__(256) void k_final(
    const float* __restrict__ ws, const float* __restrict__ finalb,
    float* __restrict__ out)
{
  const int e4 = (blockIdx.x*256 + threadIdx.x)*4;
  const int i = e4 >> 6;
  const int t = e4 & 63;
  const float a = ws[O_AOP + i];
  const float fb = finalb[0];
  const float4 bp = *(const float4*)&ws[O_BPLACE + e4];
  const float4 cv = *(const float4*)&ws[O_CVEC + t];
  float4 o4;
  o4.x = a + bp.x + cv.x + fb;
  o4.y = a + bp.y + cv.y + fb;
  o4.z = a + bp.z + cv.z + fb;
  o4.w = a + bp.w + cv.w + fb;
  *(float4*)&out[e4] = o4;
}

extern "C" void kernel_launch(void* const* d_in, const int* in_sizes, int n_in,
                              void* d_out, int out_size, void* d_ws, size_t ws_size,
                              hipStream_t stream)
{
  (void)in_sizes; (void)n_in; (void)out_size;
  if (ws_size < (size_t)O_TOTAL * sizeof(float)) return;

  const float* op_feats     = (const float*)d_in[0];
  const float* task_feats   = (const float*)d_in[1];
  const float* tensor_feats = (const float*)d_in[2];
  const float* link_feats   = (const float*)d_in[3];
  const float* place_feats  = (const float*)d_in[4];
  const int*   prev_src     = (const int*)d_in[5];
  const int*   prev_dst     = (const int*)d_in[6];
  const int*   link_src     = (const int*)d_in[7];
  const int*   link_dst     = (const int*)d_in[8];
  const float* op_W         = (const float*)d_in[9];
  const float* op_b         = (const float*)d_in[10];
  const float* task_W       = (const float*)d_in[11];
  const float* task_b       = (const float*)d_in[12];
  const float* eW           = (const float*)d_in[13];
  const float* eb           = (const float*)d_in[14];
  const float* gW           = (const float*)d_in[15];
  const float* gb           = (const float*)d_in[16];
  const float* finalW       = (const float*)d_in[17];
  const float* finalb       = (const float*)d_in[18];
  float* w = (float*)d_ws;
  float* out = (float*)d_out;

  k_embed<<<257, 256, 0, stream>>>(op_feats, op_W, op_b, task_feats, task_W, task_b, w);
  k_edge_place<<<384, 256, 0, stream>>>(tensor_feats, link_feats, place_feats,
                                        prev_src, prev_dst, link_src, link_dst,
                                        eW, eb, finalW, w);

  for (int l = 0; l < 6; ++l) {
    const float* oin  = w + ((l & 1) ? O_OP_B : O_OP_A);
    float*       oout = w + ((l & 1) ? O_OP_A : O_OP_B);
    const float* tin  = w + ((l & 1) ? O_TASK_B : O_TASK_A);
    float*       tout = w + ((l & 1) ? O_TASK_A : O_TASK_B);
    k_layer<<<NOPB + 4, 256, 0, stream>>>(l, gW, gb, finalW, oin, oout, tin, tout, w);
  }

  k_final<<<256, 256, 0, stream>>>(w, finalb, out);
}